// Round 2
// baseline (390.739 us; speedup 1.0000x reference)
//
#include <hip/hip_runtime.h>

// Branch MLP dispatch: B=16384 rows, E=4 experts, 512->1024->1024->512,
// relu/relu/tanh. Strategy: bucket rows by expert, pad each expert segment
// to 128-row tiles with duplicate rows (maskless GEMM), 3 bf16-MFMA GEMM
// passes with pre-transposed bf16 weights [E][N][K].
//
// Workspace layout (needs ~86 MB):
//   ctrl (64 ints): [0..3]=counts [4..7]=cursors [8..12]=padded offsets P_e
//                   [13]=nTiles
//   tileExpert[160], tileBase[160], perm[16896]
//   Wt1 (4MB bf16) | Wt2 (8MB) | Wt3 (4MB) | h1 (33MB bf16) | h2 (33MB)

#define B_N   16384
#define E_N   4
#define DIN   512
#define HID   1024
#define DOUT  512

typedef __attribute__((ext_vector_type(8))) short bf16x8;
typedef __attribute__((ext_vector_type(4))) float f32x4;

__device__ __forceinline__ unsigned short f2bf(float f) {
    unsigned int u = __float_as_uint(f);
    u += 0x7FFFu + ((u >> 16) & 1u);   // round-to-nearest-even
    return (unsigned short)(u >> 16);
}

__global__ void zero_ctrl_k(int* ctrl) {
    if (threadIdx.x < 16) ctrl[threadIdx.x] = 0;
}

__global__ void count_k(const int* __restrict__ cmd, int* __restrict__ ctrl) {
    int i = blockIdx.x * 256 + threadIdx.x;
    atomicAdd(&ctrl[cmd[i] & 3], 1);
}

__global__ void plan_k(int* __restrict__ ctrl, int* __restrict__ tileExpert,
                       int* __restrict__ tileBase) {
    if (threadIdx.x == 0) {
        int P = 0, nt = 0;
        for (int e = 0; e < 4; ++e) {
            ctrl[8 + e] = P;
            int c = ctrl[e];
            int tiles = (c + 127) >> 7;
            for (int t = 0; t < tiles; ++t) {
                tileExpert[nt] = e;
                tileBase[nt] = P + t * 128;
                ++nt;
            }
            P += tiles * 128;
        }
        ctrl[12] = P;       // total padded rows (<= 16896)
        ctrl[13] = nt;      // total tiles (<= 131)
    }
}

__global__ void scatter_k(const int* __restrict__ cmd, int* __restrict__ ctrl,
                          int* __restrict__ perm) {
    int i = blockIdx.x * 256 + threadIdx.x;
    int e = cmd[i] & 3;
    int p = atomicAdd(&ctrl[4 + e], 1);
    perm[ctrl[8 + e] + p] = i;
}

__global__ void fillpad_k(const int* __restrict__ ctrl, int* __restrict__ perm) {
    for (int e = 0; e < 4; ++e) {
        int c = ctrl[e];
        int base = ctrl[8 + e];
        int padded = ctrl[8 + e + 1] - base;   // e==3 uses ctrl[12]
        for (int j = c + (int)threadIdx.x; j < padded; j += (int)blockDim.x)
            perm[base + j] = perm[base];       // duplicate a valid same-expert row
    }
}

// Transpose+convert: Wt[e][n][k] = bf16(W[e][k][n])
template<int KD, int ND>
__global__ __launch_bounds__(256) void transw_k(const float* __restrict__ W,
                                                unsigned short* __restrict__ Wt) {
    __shared__ float t[32][33];
    int e = blockIdx.z;
    size_t base = (size_t)e * KD * ND;
    int k0 = blockIdx.x * 32, n0 = blockIdx.y * 32;
    int tx = threadIdx.x & 31, ty = threadIdx.x >> 5;   // ty in 0..7
#pragma unroll
    for (int s = 0; s < 4; ++s)
        t[ty + s * 8][tx] = W[base + (size_t)(k0 + ty + s * 8) * ND + n0 + tx];
    __syncthreads();
#pragma unroll
    for (int s = 0; s < 4; ++s)
        Wt[base + (size_t)(n0 + ty + s * 8) * KD + k0 + tx] = f2bf(t[tx][ty + s * 8]);
}

// Grouped GEMM: C = act(A @ W[e] + b[e])
// A: rows of the tile's expert (gathered fp32 x for L1, contiguous padded bf16 h
// for L2/L3). B: Wt bf16 [E][N][K]. Tile 128x128, BK=32, 4 waves, each wave a
// 64x64 quadrant (4x4 fragments of 16x16x32 MFMA).
template<int K, int N, int ACT, bool GATHER_A, bool SCATTER_OUT>
__global__ __launch_bounds__(256) void gemm_k(
    const void* __restrict__ Asrc, const unsigned short* __restrict__ Bt,
    const float* __restrict__ bias, void* __restrict__ Outp,
    const int* __restrict__ ctrl, const int* __restrict__ tileExpert,
    const int* __restrict__ tileBase, const int* __restrict__ perm)
{
    const int nTiles = ctrl[13];
    if ((int)blockIdx.x >= nTiles) return;
    const int e = tileExpert[blockIdx.x];
    const int rowBase = tileBase[blockIdx.x];
    const int n0 = blockIdx.y * 128;

    __shared__ unsigned short Als[128][40];   // stride 40 ushort = 80B (20 banks)
    __shared__ unsigned short Bls[128][40];

    const int tid = threadIdx.x;
    const int lane = tid & 63;
    const int w = tid >> 6;
    const int wm = w >> 1, wn = w & 1;        // wave quadrant
    const int lr = lane & 15, lh = lane >> 4;

    f32x4 acc[4][4] = {};

    // B staging: thread t -> n-row (t>>1), k-half (t&1)*16 ushorts (=32B)
    const int bn = tid >> 1, bh = tid & 1;
    const unsigned short* Bp = Bt + ((size_t)e * N + (size_t)(n0 + bn)) * K + bh * 16;

    const float* Af = (const float*)Asrc;
    const unsigned short* Ahp = nullptr;
    int arow[4];
    if (GATHER_A) {
#pragma unroll
        for (int s = 0; s < 4; ++s)
            arow[s] = perm[rowBase + s * 32 + (tid >> 3)];
    } else {
        Ahp = (const unsigned short*)Asrc
            + (size_t)(rowBase + (tid >> 1)) * K + (tid & 1) * 16;
    }

    for (int kb = 0; kb < K / 32; ++kb) {
        const int k0 = kb * 32;
        // global -> regs (each thread stages 32B = 16 ushorts of its half-row)
        uint4 breg0 = *(const uint4*)(Bp + k0);
        uint4 breg1 = *(const uint4*)(Bp + k0 + 8);
        float4 areg[4];
        uint4 areg0, areg1;
        if (GATHER_A) {
#pragma unroll
            for (int s = 0; s < 4; ++s)
                areg[s] = *(const float4*)(Af + (size_t)arow[s] * K + k0 + (tid & 7) * 4);
        } else {
            areg0 = *(const uint4*)(Ahp + k0);
            areg1 = *(const uint4*)(Ahp + k0 + 8);
        }
        __syncthreads();   // previous compute done reading LDS
        *(uint4*)&Bls[bn][bh * 16] = breg0;
        *(uint4*)&Bls[bn][bh * 16 + 8] = breg1;
        if (GATHER_A) {
#pragma unroll
            for (int s = 0; s < 4; ++s) {
                int row = s * 32 + (tid >> 3);
                ushort4 packed = make_ushort4(f2bf(areg[s].x), f2bf(areg[s].y),
                                              f2bf(areg[s].z), f2bf(areg[s].w));
                *(ushort4*)&Als[row][(tid & 7) * 4] = packed;
            }
        } else {
            *(uint4*)&Als[tid >> 1][(tid & 1) * 16] = areg0;
            *(uint4*)&Als[tid >> 1][(tid & 1) * 16 + 8] = areg1;
        }
        __syncthreads();
        // fragments + MFMA
        bf16x8 afr[4], bfr[4];
#pragma unroll
        for (int mi = 0; mi < 4; ++mi)
            afr[mi] = *(const bf16x8*)&Als[wm * 64 + mi * 16 + lr][lh * 8];
#pragma unroll
        for (int ni = 0; ni < 4; ++ni)
            bfr[ni] = *(const bf16x8*)&Bls[wn * 64 + ni * 16 + lr][lh * 8];
#pragma unroll
        for (int mi = 0; mi < 4; ++mi)
#pragma unroll
            for (int ni = 0; ni < 4; ++ni)
                acc[mi][ni] = __builtin_amdgcn_mfma_f32_16x16x32_bf16(
                    afr[mi], bfr[ni], acc[mi][ni], 0, 0, 0);
    }

    // epilogue: bias + activation + store
    float bv[4];
    int colv[4];
#pragma unroll
    for (int ni = 0; ni < 4; ++ni) {
        colv[ni] = n0 + wn * 64 + ni * 16 + lr;
        bv[ni] = bias[e * N + colv[ni]];
    }
#pragma unroll
    for (int mi = 0; mi < 4; ++mi) {
#pragma unroll
        for (int r = 0; r < 4; ++r) {
            int rowL = wm * 64 + mi * 16 + lh * 4 + r;   // C/D: row=(lane>>4)*4+reg
            int gRow = rowBase + rowL;
            int orow = SCATTER_OUT ? perm[gRow] : gRow;
#pragma unroll
            for (int ni = 0; ni < 4; ++ni) {
                float v = acc[mi][ni][r] + bv[ni];
                if (ACT == 0) v = fmaxf(v, 0.0f);
                else          v = tanhf(v);
                if (SCATTER_OUT)
                    ((float*)Outp)[(size_t)orow * N + colv[ni]] = v;
                else
                    ((unsigned short*)Outp)[(size_t)orow * N + colv[ni]] = f2bf(v);
            }
        }
    }
}

extern "C" void kernel_launch(void* const* d_in, const int* in_sizes, int n_in,
                              void* d_out, int out_size, void* d_ws, size_t ws_size,
                              hipStream_t stream) {
    const float* x  = (const float*)d_in[0];
    const int*   cmd= (const int*)d_in[1];
    const float* W1 = (const float*)d_in[2];
    const float* b1 = (const float*)d_in[3];
    const float* W2 = (const float*)d_in[4];
    const float* b2 = (const float*)d_in[5];
    const float* W3 = (const float*)d_in[6];
    const float* b3 = (const float*)d_in[7];
    float* out = (float*)d_out;

    char* w = (char*)d_ws;
    int* ctrl       = (int*)w;
    int* tileExpert = ctrl + 64;
    int* tileBase   = ctrl + 224;
    int* perm       = ctrl + 512;                     // 16896 ints
    unsigned short* Wt1 = (unsigned short*)(w + (1u << 17));
    unsigned short* Wt2 = (unsigned short*)(w + (1u << 17) + (4u << 20));
    unsigned short* Wt3 = (unsigned short*)(w + (1u << 17) + (12u << 20));
    unsigned short* h1  = (unsigned short*)(w + (1u << 17) + (16u << 20));
    unsigned short* h2  = h1 + (size_t)16896 * 1024;

    zero_ctrl_k<<<1, 64, 0, stream>>>(ctrl);
    count_k<<<B_N / 256, 256, 0, stream>>>(cmd, ctrl);
    plan_k<<<1, 64, 0, stream>>>(ctrl, tileExpert, tileBase);
    scatter_k<<<B_N / 256, 256, 0, stream>>>(cmd, ctrl, perm);
    fillpad_k<<<1, 256, 0, stream>>>(ctrl, perm);

    transw_k<512, 1024><<<dim3(16, 32, 4), 256, 0, stream>>>(W1, Wt1);
    transw_k<1024, 1024><<<dim3(32, 32, 4), 256, 0, stream>>>(W2, Wt2);
    transw_k<1024, 512><<<dim3(32, 16, 4), 256, 0, stream>>>(W3, Wt3);

    gemm_k<512, 1024, 0, true, false><<<dim3(136, 8), 256, 0, stream>>>(
        x, Wt1, b1, h1, ctrl, tileExpert, tileBase, perm);
    gemm_k<1024, 1024, 0, false, false><<<dim3(136, 8), 256, 0, stream>>>(
        h1, Wt2, b2, h2, ctrl, tileExpert, tileBase, perm);
    gemm_k<1024, 512, 1, false, true><<<dim3(136, 4), 256, 0, stream>>>(
        h2, Wt3, b3, out, ctrl, tileExpert, tileBase, perm);
}

// Round 3
// 233.095 us; speedup vs baseline: 1.6763x; 1.6763x over previous
//
#include <hip/hip_runtime.h>

// Branch MLP dispatch: B=16384 rows, E=4 experts, 512->1024->1024->512,
// relu/relu/tanh. Strategy: bucket rows by expert, pad each expert segment
// to 128-row tiles with duplicate rows (maskless GEMM), 3 bf16-MFMA GEMM
// passes with pre-transposed bf16 weights [E][N][K].
//
// Workspace layout (needs ~86 MB):
//   ctrl (64 ints): [0..3]=counts [4..7]=cursors [8..12]=padded offsets P_e
//                   [13]=nTiles
//   tileExpert[160], tileBase[160], perm[16896]
//   Wt1 (4MB bf16) | Wt2 (8MB) | Wt3 (4MB) | h1 (33MB bf16) | h2 (33MB)

#define B_N   16384
#define E_N   4
#define DIN   512
#define HID   1024
#define DOUT  512

typedef __attribute__((ext_vector_type(8))) short bf16x8;
typedef __attribute__((ext_vector_type(4))) float f32x4;

__device__ __forceinline__ unsigned short f2bf(float f) {
    unsigned int u = __float_as_uint(f);
    u += 0x7FFFu + ((u >> 16) & 1u);   // round-to-nearest-even
    return (unsigned short)(u >> 16);
}

__device__ __forceinline__ float fast_tanh(float x) {
    // tanh(x) = (e^{2x}-1)/(e^{2x}+1), e^{2x} = 2^{2x*log2(e)}; clamp keeps
    // exp2 in range (tanh(9) = 1-3e-8, below bf16/threshold resolution).
    x = fminf(fmaxf(x, -9.0f), 9.0f);
    float t = __builtin_amdgcn_exp2f(x * 2.8853900817779268f);
    return (t - 1.0f) * __builtin_amdgcn_rcpf(t + 1.0f);
}

__global__ void zero_ctrl_k(int* ctrl) {
    if (threadIdx.x < 16) ctrl[threadIdx.x] = 0;
}

// Wave-aggregated histogram: 4 atomics per wave instead of 64.
__global__ void count_k(const int* __restrict__ cmd, int* __restrict__ ctrl) {
    int i = blockIdx.x * 256 + threadIdx.x;
    int e = cmd[i] & 3;
    int lane = threadIdx.x & 63;
#pragma unroll
    for (int ee = 0; ee < 4; ++ee) {
        unsigned long long mask = __ballot(e == ee);
        int leader = __ffsll((unsigned long long)mask) - 1;
        if (mask && lane == leader)
            atomicAdd(&ctrl[ee], __popcll(mask));
    }
}

__global__ void plan_k(int* __restrict__ ctrl, int* __restrict__ tileExpert,
                       int* __restrict__ tileBase) {
    if (threadIdx.x == 0) {
        int P = 0, nt = 0;
        for (int e = 0; e < 4; ++e) {
            ctrl[8 + e] = P;
            int c = ctrl[e];
            int tiles = (c + 127) >> 7;
            for (int t = 0; t < tiles; ++t) {
                tileExpert[nt] = e;
                tileBase[nt] = P + t * 128;
                ++nt;
            }
            P += tiles * 128;
        }
        ctrl[12] = P;       // total padded rows (<= 16896)
        ctrl[13] = nt;      // total tiles (<= 131)
    }
}

// Wave-aggregated scatter: leader takes one atomicAdd(popcount) per expert,
// lanes place themselves at base + rank-in-ballot. Value-deterministic.
__global__ void scatter_k(const int* __restrict__ cmd, int* __restrict__ ctrl,
                          int* __restrict__ perm) {
    int i = blockIdx.x * 256 + threadIdx.x;
    int e = cmd[i] & 3;
    int lane = threadIdx.x & 63;
#pragma unroll
    for (int ee = 0; ee < 4; ++ee) {
        unsigned long long mask = __ballot(e == ee);
        if (e == ee) {
            int leader = __ffsll((unsigned long long)mask) - 1;
            int rank = __popcll(mask & ((1ull << lane) - 1ull));
            int wbase = 0;
            if (lane == leader)
                wbase = atomicAdd(&ctrl[4 + ee], __popcll(mask));
            wbase = __builtin_amdgcn_readfirstlane(wbase);
            perm[ctrl[8 + ee] + wbase + rank] = i;
        }
    }
}

__global__ void fillpad_k(const int* __restrict__ ctrl, int* __restrict__ perm) {
    for (int e = 0; e < 4; ++e) {
        int c = ctrl[e];
        int base = ctrl[8 + e];
        int padded = ctrl[8 + e + 1] - base;   // e==3 uses ctrl[12]
        for (int j = c + (int)threadIdx.x; j < padded; j += (int)blockDim.x)
            perm[base + j] = perm[base];       // duplicate a valid same-expert row
    }
}

// Transpose+convert: Wt[e][n][k] = bf16(W[e][k][n])
template<int KD, int ND>
__global__ __launch_bounds__(256) void transw_k(const float* __restrict__ W,
                                                unsigned short* __restrict__ Wt) {
    __shared__ float t[32][33];
    int e = blockIdx.z;
    size_t base = (size_t)e * KD * ND;
    int k0 = blockIdx.x * 32, n0 = blockIdx.y * 32;
    int tx = threadIdx.x & 31, ty = threadIdx.x >> 5;   // ty in 0..7
#pragma unroll
    for (int s = 0; s < 4; ++s)
        t[ty + s * 8][tx] = W[base + (size_t)(k0 + ty + s * 8) * ND + n0 + tx];
    __syncthreads();
#pragma unroll
    for (int s = 0; s < 4; ++s)
        Wt[base + (size_t)(n0 + ty + s * 8) * KD + k0 + tx] = f2bf(t[tx][ty + s * 8]);
}

// Grouped GEMM: C = act(A @ W[e] + b[e])
// A: rows of the tile's expert (gathered fp32 x for L1, contiguous padded bf16 h
// for L2/L3). B: Wt bf16 [E][N][K]. Tile 128x128, BK=32, 4 waves, each wave a
// 64x64 quadrant (4x4 fragments of 16x16x32 MFMA).
template<int K, int N, int ACT, bool GATHER_A, bool SCATTER_OUT>
__global__ __launch_bounds__(256) void gemm_k(
    const void* __restrict__ Asrc, const unsigned short* __restrict__ Bt,
    const float* __restrict__ bias, void* __restrict__ Outp,
    const int* __restrict__ ctrl, const int* __restrict__ tileExpert,
    const int* __restrict__ tileBase, const int* __restrict__ perm)
{
    const int nTiles = ctrl[13];
    if ((int)blockIdx.x >= nTiles) return;
    const int e = tileExpert[blockIdx.x];
    const int rowBase = tileBase[blockIdx.x];
    const int n0 = blockIdx.y * 128;

    __shared__ unsigned short Als[128][40];   // stride 40 ushort = 80B (20 banks)
    __shared__ unsigned short Bls[128][40];

    const int tid = threadIdx.x;
    const int lane = tid & 63;
    const int w = tid >> 6;
    const int wm = w >> 1, wn = w & 1;        // wave quadrant
    const int lr = lane & 15, lh = lane >> 4;

    f32x4 acc[4][4] = {};

    // B staging: thread t -> n-row (t>>1), k-half (t&1)*16 ushorts (=32B)
    const int bn = tid >> 1, bh = tid & 1;
    const unsigned short* Bp = Bt + ((size_t)e * N + (size_t)(n0 + bn)) * K + bh * 16;

    const float* Af = (const float*)Asrc;
    const unsigned short* Ahp = nullptr;
    int arow[4];
    if (GATHER_A) {
#pragma unroll
        for (int s = 0; s < 4; ++s)
            arow[s] = perm[rowBase + s * 32 + (tid >> 3)];
    } else {
        Ahp = (const unsigned short*)Asrc
            + (size_t)(rowBase + (tid >> 1)) * K + (tid & 1) * 16;
    }

    for (int kb = 0; kb < K / 32; ++kb) {
        const int k0 = kb * 32;
        // global -> regs (each thread stages 32B = 16 ushorts of its half-row)
        uint4 breg0 = *(const uint4*)(Bp + k0);
        uint4 breg1 = *(const uint4*)(Bp + k0 + 8);
        float4 areg[4];
        uint4 areg0, areg1;
        if (GATHER_A) {
#pragma unroll
            for (int s = 0; s < 4; ++s)
                areg[s] = *(const float4*)(Af + (size_t)arow[s] * K + k0 + (tid & 7) * 4);
        } else {
            areg0 = *(const uint4*)(Ahp + k0);
            areg1 = *(const uint4*)(Ahp + k0 + 8);
        }
        __syncthreads();   // previous compute done reading LDS
        *(uint4*)&Bls[bn][bh * 16] = breg0;
        *(uint4*)&Bls[bn][bh * 16 + 8] = breg1;
        if (GATHER_A) {
#pragma unroll
            for (int s = 0; s < 4; ++s) {
                int row = s * 32 + (tid >> 3);
                ushort4 packed = make_ushort4(f2bf(areg[s].x), f2bf(areg[s].y),
                                              f2bf(areg[s].z), f2bf(areg[s].w));
                *(ushort4*)&Als[row][(tid & 7) * 4] = packed;
            }
        } else {
            *(uint4*)&Als[tid >> 1][(tid & 1) * 16] = areg0;
            *(uint4*)&Als[tid >> 1][(tid & 1) * 16 + 8] = areg1;
        }
        __syncthreads();
        // fragments + MFMA
        bf16x8 afr[4], bfr[4];
#pragma unroll
        for (int mi = 0; mi < 4; ++mi)
            afr[mi] = *(const bf16x8*)&Als[wm * 64 + mi * 16 + lr][lh * 8];
#pragma unroll
        for (int ni = 0; ni < 4; ++ni)
            bfr[ni] = *(const bf16x8*)&Bls[wn * 64 + ni * 16 + lr][lh * 8];
#pragma unroll
        for (int mi = 0; mi < 4; ++mi)
#pragma unroll
            for (int ni = 0; ni < 4; ++ni)
                acc[mi][ni] = __builtin_amdgcn_mfma_f32_16x16x32_bf16(
                    afr[mi], bfr[ni], acc[mi][ni], 0, 0, 0);
    }

    // epilogue: bias + activation + store
    float bv[4];
    int colv[4];
#pragma unroll
    for (int ni = 0; ni < 4; ++ni) {
        colv[ni] = n0 + wn * 64 + ni * 16 + lr;
        bv[ni] = bias[e * N + colv[ni]];
    }
#pragma unroll
    for (int mi = 0; mi < 4; ++mi) {
#pragma unroll
        for (int r = 0; r < 4; ++r) {
            int rowL = wm * 64 + mi * 16 + lh * 4 + r;   // C/D: row=(lane>>4)*4+reg
            int gRow = rowBase + rowL;
            int orow = SCATTER_OUT ? perm[gRow] : gRow;
#pragma unroll
            for (int ni = 0; ni < 4; ++ni) {
                float v = acc[mi][ni][r] + bv[ni];
                if (ACT == 0) v = fmaxf(v, 0.0f);
                else          v = fast_tanh(v);
                if (SCATTER_OUT)
                    ((float*)Outp)[(size_t)orow * N + colv[ni]] = v;
                else
                    ((unsigned short*)Outp)[(size_t)orow * N + colv[ni]] = f2bf(v);
            }
        }
    }
}

extern "C" void kernel_launch(void* const* d_in, const int* in_sizes, int n_in,
                              void* d_out, int out_size, void* d_ws, size_t ws_size,
                              hipStream_t stream) {
    const float* x  = (const float*)d_in[0];
    const int*   cmd= (const int*)d_in[1];
    const float* W1 = (const float*)d_in[2];
    const float* b1 = (const float*)d_in[3];
    const float* W2 = (const float*)d_in[4];
    const float* b2 = (const float*)d_in[5];
    const float* W3 = (const float*)d_in[6];
    const float* b3 = (const float*)d_in[7];
    float* out = (float*)d_out;

    char* w = (char*)d_ws;
    int* ctrl       = (int*)w;
    int* tileExpert = ctrl + 64;
    int* tileBase   = ctrl + 224;
    int* perm       = ctrl + 512;                     // 16896 ints
    unsigned short* Wt1 = (unsigned short*)(w + (1u << 17));
    unsigned short* Wt2 = (unsigned short*)(w + (1u << 17) + (4u << 20));
    unsigned short* Wt3 = (unsigned short*)(w + (1u << 17) + (12u << 20));
    unsigned short* h1  = (unsigned short*)(w + (1u << 17) + (16u << 20));
    unsigned short* h2  = h1 + (size_t)16896 * 1024;

    zero_ctrl_k<<<1, 64, 0, stream>>>(ctrl);
    count_k<<<B_N / 256, 256, 0, stream>>>(cmd, ctrl);
    plan_k<<<1, 64, 0, stream>>>(ctrl, tileExpert, tileBase);
    scatter_k<<<B_N / 256, 256, 0, stream>>>(cmd, ctrl, perm);
    fillpad_k<<<1, 256, 0, stream>>>(ctrl, perm);

    transw_k<512, 1024><<<dim3(16, 32, 4), 256, 0, stream>>>(W1, Wt1);
    transw_k<1024, 1024><<<dim3(32, 32, 4), 256, 0, stream>>>(W2, Wt2);
    transw_k<1024, 512><<<dim3(32, 16, 4), 256, 0, stream>>>(W3, Wt3);

    gemm_k<512, 1024, 0, true, false><<<dim3(136, 8), 256, 0, stream>>>(
        x, Wt1, b1, h1, ctrl, tileExpert, tileBase, perm);
    gemm_k<1024, 1024, 0, false, false><<<dim3(136, 8), 256, 0, stream>>>(
        h1, Wt2, b2, h2, ctrl, tileExpert, tileBase, perm);
    gemm_k<1024, 512, 1, false, true><<<dim3(136, 4), 256, 0, stream>>>(
        h2, Wt3, b3, out, ctrl, tileExpert, tileBase, perm);
}

// Round 4
// 183.147 us; speedup vs baseline: 2.1335x; 1.2727x over previous
//
#include <hip/hip_runtime.h>

// Branch MLP dispatch: B=16384 rows, E=4 experts, 512->1024->1024->512,
// relu/relu/tanh. Bucket rows by expert, pad each expert segment to 128-row
// tiles with duplicate rows (maskless GEMM), 3 bf16-MFMA GEMM passes with
// pre-transposed bf16 weights [E][N][K]. GEMM staging via global_load_lds
// (width=16) into linear [128][32] LDS tiles (m97 structure).

#define B_N   16384
#define E_N   4
#define DIN   512
#define HID   1024
#define DOUT  512

typedef __attribute__((ext_vector_type(8))) short bf16x8;
typedef __attribute__((ext_vector_type(4))) float f32x4;
typedef __attribute__((address_space(3))) unsigned int lds_u32;
typedef const __attribute__((address_space(1))) unsigned int glb_u32;

__device__ __forceinline__ void gll16(const void* g, void* l) {
    __builtin_amdgcn_global_load_lds((glb_u32*)g, (lds_u32*)l, 16, 0, 0);
}

__device__ __forceinline__ unsigned short f2bf(float f) {
    unsigned int u = __float_as_uint(f);
    u += 0x7FFFu + ((u >> 16) & 1u);   // round-to-nearest-even
    return (unsigned short)(u >> 16);
}

__device__ __forceinline__ float fast_tanh(float x) {
    x = fminf(fmaxf(x, -9.0f), 9.0f);
    float t = __builtin_amdgcn_exp2f(x * 2.8853900817779268f);
    return (t - 1.0f) * __builtin_amdgcn_rcpf(t + 1.0f);
}

__global__ void zero_ctrl_k(int* ctrl) {
    if (threadIdx.x < 16) ctrl[threadIdx.x] = 0;
}

// Wave-aggregated histogram: 4 atomics per wave instead of 64.
__global__ void count_k(const int* __restrict__ cmd, int* __restrict__ ctrl) {
    int i = blockIdx.x * 256 + threadIdx.x;
    int e = cmd[i] & 3;
    int lane = threadIdx.x & 63;
#pragma unroll
    for (int ee = 0; ee < 4; ++ee) {
        unsigned long long mask = __ballot(e == ee);
        int leader = __ffsll((unsigned long long)mask) - 1;
        if (mask && lane == leader)
            atomicAdd(&ctrl[ee], __popcll(mask));
    }
}

__global__ void plan_k(int* __restrict__ ctrl, int* __restrict__ tileExpert,
                       int* __restrict__ tileBase) {
    if (threadIdx.x == 0) {
        int P = 0, nt = 0;
        for (int e = 0; e < 4; ++e) {
            ctrl[8 + e] = P;
            int c = ctrl[e];
            int tiles = (c + 127) >> 7;
            for (int t = 0; t < tiles; ++t) {
                tileExpert[nt] = e;
                tileBase[nt] = P + t * 128;
                ++nt;
            }
            P += tiles * 128;
        }
        ctrl[12] = P;       // total padded rows (<= 16896)
        ctrl[13] = nt;      // total tiles (<= 131)
    }
}

// Wave-aggregated scatter: one atomicAdd(popcount) per wave per expert.
__global__ void scatter_k(const int* __restrict__ cmd, int* __restrict__ ctrl,
                          int* __restrict__ perm) {
    int i = blockIdx.x * 256 + threadIdx.x;
    int e = cmd[i] & 3;
    int lane = threadIdx.x & 63;
#pragma unroll
    for (int ee = 0; ee < 4; ++ee) {
        unsigned long long mask = __ballot(e == ee);
        if (e == ee) {
            int leader = __ffsll((unsigned long long)mask) - 1;
            int rank = __popcll(mask & ((1ull << lane) - 1ull));
            int wbase = 0;
            if (lane == leader)
                wbase = atomicAdd(&ctrl[4 + ee], __popcll(mask));
            wbase = __builtin_amdgcn_readfirstlane(wbase);
            perm[ctrl[8 + ee] + wbase + rank] = i;
        }
    }
}

__global__ void fillpad_k(const int* __restrict__ ctrl, int* __restrict__ perm) {
    for (int e = 0; e < 4; ++e) {
        int c = ctrl[e];
        int base = ctrl[8 + e];
        int padded = ctrl[8 + e + 1] - base;   // e==3 uses ctrl[12]
        for (int j = c + (int)threadIdx.x; j < padded; j += (int)blockDim.x)
            perm[base + j] = perm[base];       // duplicate a valid same-expert row
    }
}

// Transpose+convert: Wt[e][n][k] = bf16(W[e][k][n])
template<int KD, int ND>
__global__ __launch_bounds__(256) void transw_k(const float* __restrict__ W,
                                                unsigned short* __restrict__ Wt) {
    __shared__ float t[32][33];
    int e = blockIdx.z;
    size_t base = (size_t)e * KD * ND;
    int k0 = blockIdx.x * 32, n0 = blockIdx.y * 32;
    int tx = threadIdx.x & 31, ty = threadIdx.x >> 5;   // ty in 0..7
#pragma unroll
    for (int s = 0; s < 4; ++s)
        t[ty + s * 8][tx] = W[base + (size_t)(k0 + ty + s * 8) * ND + n0 + tx];
    __syncthreads();
#pragma unroll
    for (int s = 0; s < 4; ++s)
        Wt[base + (size_t)(n0 + ty + s * 8) * KD + k0 + tx] = f2bf(t[tx][ty + s * 8]);
}

// Grouped GEMM: C = act(A @ W[e] + b[e]).
// Tile 128x128, BK=32, 4 waves, each wave a 64x64 quadrant (4x4 frags of
// 16x16x32 MFMA). B (and A for layers 2/3) staged by global_load_lds into
// linear [128][32] LDS; layer-1 A reg-staged (fp32 gather + f2bf) into a
// stride-40 padded tile.
template<int K, int N, int ACT, bool GATHER_A, bool SCATTER_OUT>
__global__ __launch_bounds__(256) void gemm_k(
    const void* __restrict__ Asrc, const unsigned short* __restrict__ Bt,
    const float* __restrict__ bias, void* __restrict__ Outp,
    const int* __restrict__ ctrl, const int* __restrict__ tileExpert,
    const int* __restrict__ tileBase, const int* __restrict__ perm)
{
    const int nTiles = ctrl[13];
    if ((int)blockIdx.x >= nTiles) return;
    const int e = tileExpert[blockIdx.x];
    const int rowBase = tileBase[blockIdx.x];
    const int n0 = blockIdx.y * 128;

    constexpr int AST = GATHER_A ? 40 : 32;   // pad A stride only when ds_write-staged
    __shared__ unsigned short Als[128][AST];
    __shared__ unsigned short Bls[128][32];   // linear: byte offset == tid*16

    const int tid = threadIdx.x;
    const int lane = tid & 63;
    const int w = tid >> 6;
    const int wm = w >> 1, wn = w & 1;        // wave quadrant
    const int lr = lane & 15, lh = lane >> 4;

    f32x4 acc[4][4] = {};

    // global_load_lds staging indices: thread t -> row t>>2 (and +64), 16B seg t&3
    const int sr = tid >> 2;
    const int sc = (tid & 3) * 8;             // ushort column
    const unsigned short* Bb = Bt + ((size_t)e * N + (size_t)n0) * K;
    const unsigned short* Ab = (const unsigned short*)Asrc + (size_t)rowBase * K;

    const float* Af = (const float*)Asrc;
    int arow[4];
    if (GATHER_A) {
#pragma unroll
        for (int s = 0; s < 4; ++s)
            arow[s] = perm[rowBase + s * 32 + (tid >> 3)];
    }

    for (int kb = 0; kb < K / 32; ++kb) {
        const int k0 = kb * 32;
        float4 areg[4];
        if (GATHER_A) {
#pragma unroll
            for (int s = 0; s < 4; ++s)
                areg[s] = *(const float4*)(Af + (size_t)arow[s] * K + k0 + (tid & 7) * 4);
        }
        __syncthreads();   // previous iteration's LDS reads complete
        gll16(Bb + (size_t)sr * K + k0 + sc, &Bls[sr][sc]);
        gll16(Bb + (size_t)(sr + 64) * K + k0 + sc, &Bls[sr + 64][sc]);
        if (GATHER_A) {
#pragma unroll
            for (int s = 0; s < 4; ++s) {
                int row = s * 32 + (tid >> 3);
                ushort4 packed = make_ushort4(f2bf(areg[s].x), f2bf(areg[s].y),
                                              f2bf(areg[s].z), f2bf(areg[s].w));
                *(ushort4*)&Als[row][(tid & 7) * 4] = packed;
            }
        } else {
            gll16(Ab + (size_t)sr * K + k0 + sc, &Als[sr][sc]);
            gll16(Ab + (size_t)(sr + 64) * K + k0 + sc, &Als[sr + 64][sc]);
        }
        __syncthreads();   // compiler drains vmcnt/lgkmcnt before s_barrier
        // fragments + MFMA
        bf16x8 afr[4], bfr[4];
#pragma unroll
        for (int mi = 0; mi < 4; ++mi)
            afr[mi] = *(const bf16x8*)&Als[wm * 64 + mi * 16 + lr][lh * 8];
#pragma unroll
        for (int ni = 0; ni < 4; ++ni)
            bfr[ni] = *(const bf16x8*)&Bls[wn * 64 + ni * 16 + lr][lh * 8];
#pragma unroll
        for (int mi = 0; mi < 4; ++mi)
#pragma unroll
            for (int ni = 0; ni < 4; ++ni)
                acc[mi][ni] = __builtin_amdgcn_mfma_f32_16x16x32_bf16(
                    afr[mi], bfr[ni], acc[mi][ni], 0, 0, 0);
    }

    // epilogue: bias + activation + store
    float bv[4];
    int colv[4];
#pragma unroll
    for (int ni = 0; ni < 4; ++ni) {
        colv[ni] = n0 + wn * 64 + ni * 16 + lr;
        bv[ni] = bias[e * N + colv[ni]];
    }
#pragma unroll
    for (int mi = 0; mi < 4; ++mi) {
#pragma unroll
        for (int r = 0; r < 4; ++r) {
            int rowL = wm * 64 + mi * 16 + lh * 4 + r;   // C/D: row=(lane>>4)*4+reg
            int gRow = rowBase + rowL;
            int orow = SCATTER_OUT ? perm[gRow] : gRow;
#pragma unroll
            for (int ni = 0; ni < 4; ++ni) {
                float v = acc[mi][ni][r] + bv[ni];
                if (ACT == 0) v = fmaxf(v, 0.0f);
                else          v = fast_tanh(v);
                if (SCATTER_OUT)
                    ((float*)Outp)[(size_t)orow * N + colv[ni]] = v;
                else
                    ((unsigned short*)Outp)[(size_t)orow * N + colv[ni]] = f2bf(v);
            }
        }
    }
}

extern "C" void kernel_launch(void* const* d_in, const int* in_sizes, int n_in,
                              void* d_out, int out_size, void* d_ws, size_t ws_size,
                              hipStream_t stream) {
    const float* x  = (const float*)d_in[0];
    const int*   cmd= (const int*)d_in[1];
    const float* W1 = (const float*)d_in[2];
    const float* b1 = (const float*)d_in[3];
    const float* W2 = (const float*)d_in[4];
    const float* b2 = (const float*)d_in[5];
    const float* W3 = (const float*)d_in[6];
    const float* b3 = (const float*)d_in[7];
    float* out = (float*)d_out;

    char* w = (char*)d_ws;
    int* ctrl       = (int*)w;
    int* tileExpert = ctrl + 64;
    int* tileBase   = ctrl + 224;
    int* perm       = ctrl + 512;                     // 16896 ints
    unsigned short* Wt1 = (unsigned short*)(w + (1u << 17));
    unsigned short* Wt2 = (unsigned short*)(w + (1u << 17) + (4u << 20));
    unsigned short* Wt3 = (unsigned short*)(w + (1u << 17) + (12u << 20));
    unsigned short* h1  = (unsigned short*)(w + (1u << 17) + (16u << 20));
    unsigned short* h2  = h1 + (size_t)16896 * 1024;

    zero_ctrl_k<<<1, 64, 0, stream>>>(ctrl);
    count_k<<<B_N / 256, 256, 0, stream>>>(cmd, ctrl);
    plan_k<<<1, 64, 0, stream>>>(ctrl, tileExpert, tileBase);
    scatter_k<<<B_N / 256, 256, 0, stream>>>(cmd, ctrl, perm);
    fillpad_k<<<1, 256, 0, stream>>>(ctrl, perm);

    transw_k<512, 1024><<<dim3(16, 32, 4), 256, 0, stream>>>(W1, Wt1);
    transw_k<1024, 1024><<<dim3(32, 32, 4), 256, 0, stream>>>(W2, Wt2);
    transw_k<1024, 512><<<dim3(32, 16, 4), 256, 0, stream>>>(W3, Wt3);

    gemm_k<512, 1024, 0, true, false><<<dim3(136, 8), 256, 0, stream>>>(
        x, Wt1, b1, h1, ctrl, tileExpert, tileBase, perm);
    gemm_k<1024, 1024, 0, false, false><<<dim3(136, 8), 256, 0, stream>>>(
        h1, Wt2, b2, h2, ctrl, tileExpert, tileBase, perm);
    gemm_k<1024, 512, 1, false, true><<<dim3(136, 4), 256, 0, stream>>>(
        h2, Wt3, b3, out, ctrl, tileExpert, tileBase, perm);
}